// Round 4
// baseline (99.189 us; speedup 1.0000x reference)
//
#include <hip/hip_runtime.h>

typedef unsigned short u16;
typedef unsigned int u32;
typedef __attribute__((ext_vector_type(8))) short bf16x8;
typedef __attribute__((ext_vector_type(4))) float f32x4;
typedef __attribute__((ext_vector_type(4))) u32 u32x4;

__device__ __forceinline__ u32 cvtpk(float lo, float hi) {
    u32 r; asm("v_cvt_pk_bf16_f32 %0, %1, %2" : "=v"(r) : "v"(lo), "v"(hi)); return r;
}
__device__ __forceinline__ u16 f2bf1(float f) { return (u16)(cvtpk(f, f) & 0xffffu); }

__device__ __forceinline__ u16 f2bf(float f) {   // setup kernels only
    union { float f; unsigned u; } v; v.f = f;
    unsigned r = (v.u + 0x7FFFu + ((v.u >> 16) & 1u)) >> 16;
    return (u16)r;
}

// ---------------- setup kernel 1: edge softmax into ws (padded 32x32 grid) ---
__global__ void edge_softmax_k(const float* __restrict__ rg,
                               const float* __restrict__ gb,
                               float* __restrict__ ew) {
    int tid = blockIdx.x * 256 + threadIdx.x;      // 0..1023 = i*32+j
    if (tid >= 1024) return;
    int i = tid >> 5, j = tid & 31;
    float w0 = 0.f, w1 = 0.f;
    if (i != j) {
        int e = i * 31 + j - (j > i ? 1 : 0);      // original edge index
        float a0 = (rg[e * 2 + 0] + gb[e * 2 + 0]) * 2.0f;   // /TAU, TAU=0.5
        float a1 = (rg[e * 2 + 1] + gb[e * 2 + 1]) * 2.0f;
        float m = fmaxf(a0, a1);
        float e0 = expf(a0 - m), e1 = expf(a1 - m);
        float s = e0 + e1;
        w0 = e0 / s; w1 = e1 / s;
    }
    ew[tid * 2 + 0] = w0;
    ew[tid * 2 + 1] = w1;
}

// ---------------- setup kernel 2: pack weights into MFMA fragment order ------
// B-frag (16x16x32): lane l supplies B[32*s + 8*(l>>4) + j][16*t + (l&15)]
// w1tp: A-frag of W1^T with output-col permutation pi(t,a,b)=32(t>>1)+8a+4(t&1)+b
//       lane l, elem j: W1[k][8*(l>>4)+j][pi(t, (l&15)>>2, l&3)]
__global__ void pack_weights_k(const float* __restrict__ W1,   // (2,32,64)
                               const float* __restrict__ W2,   // (2,64,64)
                               const float* __restrict__ OW1,  // (80,64)
                               const float* __restrict__ OW2,  // (64,64)
                               const float* __restrict__ OW3,  // (64,16)
                               u16* __restrict__ wp) {
    int tid = blockIdx.x * 256 + threadIdx.x;
    if (tid < 4096) {                                     // w1tp [k][t][lane][8]
        int j = tid & 7, l = (tid >> 3) & 63, t = (tid >> 9) & 3, k = tid >> 11;
        int kk = 8 * (l >> 4) + j;
        int n  = 32 * (t >> 1) + 8 * ((l & 15) >> 2) + 4 * (t & 1) + (l & 3);
        wp[tid] = f2bf(W1[k * 2048 + kk * 64 + n]);
    } else if (tid < 12288) {                             // w2p [k][s][t][lane][8]
        int x = tid - 4096;
        int j = x & 7, l = (x >> 3) & 63, t = (x >> 9) & 3, s = (x >> 11) & 1, k = x >> 12;
        int kk = 32 * s + 8 * (l >> 4) + j, n = 16 * t + (l & 15);
        wp[tid] = f2bf(W2[k * 4096 + kk * 64 + n]);
    } else if (tid < 18432) {                             // ow1p [s3][t][lane][8], K=80 pad 96
        int x = tid - 12288;
        int j = x & 7, l = (x >> 3) & 63, t = (x >> 9) & 3, s = x >> 11;
        int kk = 32 * s + 8 * (l >> 4) + j, n = 16 * t + (l & 15);
        wp[tid] = f2bf(kk < 80 ? OW1[kk * 64 + n] : 0.f);
    } else if (tid < 22528) {                             // ow2p [s2][t][lane][8]
        int x = tid - 18432;
        int j = x & 7, l = (x >> 3) & 63, t = (x >> 9) & 3, s = x >> 11;
        int kk = 32 * s + 8 * (l >> 4) + j, n = 16 * t + (l & 15);
        wp[tid] = f2bf(OW2[kk * 64 + n]);
    } else if (tid < 23552) {                             // ow3p [s2][lane][8], N=16
        int x = tid - 22528;
        int j = x & 7, l = (x >> 3) & 63, s = x >> 9;
        int kk = 32 * s + 8 * (l >> 4) + j, n = (l & 15);
        wp[tid] = f2bf(OW3[kk * 16 + n]);
    }
}

// ---------------- main fused kernel: one block per (b, tp) -------------------
// NOTE: no waves-per-EU hint. r1/r2 pinned at 2 blocks/CU with (256,2) even
// though LDS (36.9KB) and VGPR (84) allow 4; (256,4) miscompiled (NaN).
// Let the runtime pack by actual resources.
__global__ __launch_bounds__(256) void nri_decoder_k(
    const float* __restrict__ inputs,   // (32,32,64,16)
    const float* __restrict__ mb1, const float* __restrict__ mb2,
    const float* __restrict__ ob1, const float* __restrict__ ob2,
    const float* __restrict__ ob3,
    const float* __restrict__ ew,       // (1024,2) padded edge weights
    const u16*  __restrict__ wp,        // packed weights
    float* __restrict__ out)            // (32,32,63,16)
{
    __shared__ float xsf[32][16];
    __shared__ __align__(16) u16 xsb[32][24];       // 48B rows
    __shared__ __align__(16) float agg2[2][32][68]; // per-k partial agg, 272B rows
    __shared__ __align__(16) u16 augb[32][104];     // [xs16|agg64|pad16], 208B rows
    __shared__ __align__(16) u16 p1b[32][72];
    __shared__ __align__(16) u16 p2b[32][72];

    const int tid = threadIdx.x;
    const int w = tid >> 6, lane = tid & 63, g = lane >> 4, lr = lane & 15;
    const int kw = w >> 1, w01 = w & 1;             // wave's k-component / receiver half
    const int b = blockIdx.x >> 5, tp = blockIdx.x & 31;

    const u16* w1tp = wp;
    const u16* w2p  = wp + 4096;
    const u16* ow1p = wp + 12288;
    const u16* ow2p = wp + 18432;
    const u16* ow3p = wp + 22528;

    // load xs (timestep 2*tp); init augb xs-part and zero pad
    for (int idx = tid; idx < 512; idx += 256) {
        int a = idx >> 4, d = idx & 15;
        float v = inputs[(((b * 32 + a) * 64) + 2 * tp) * 16 + d];
        u16 bv = f2bf1(v);
        xsf[a][d] = v;
        xsb[a][d] = bv;
        augb[a][d] = bv;
        augb[a][80 + d] = 0;
    }

    // per-wave persistent fragments (k = kw only)
    bf16x8 w1t[4], w2f[2][4];
#pragma unroll
    for (int t = 0; t < 4; ++t)
        w1t[t] = *(const bf16x8*)(w1tp + ((kw * 4 + t) * 64 + lane) * 8);
#pragma unroll
    for (int s = 0; s < 2; ++s)
#pragma unroll
        for (int t = 0; t < 4; ++t)
            w2f[s][t] = *(const bf16x8*)(w2p + (((kw * 2 + s) * 4 + t) * 64 + lane) * 8);

    f32x4 b1c[4];
    float b2r[4];
#pragma unroll
    for (int t = 0; t < 4; ++t) {
#pragma unroll
        for (int r = 0; r < 4; ++r)
            b1c[t][r] = mb1[kw * 64 + 32 * (t >> 1) + 8 * g + 4 * (t & 1) + r];
        b2r[t] = mb2[kw * 64 + 16 * t + lr];
    }
    float o1r[4], o2r[4];
#pragma unroll
    for (int t = 0; t < 4; ++t) { o1r[t] = ob1[16 * t + lr]; o2r[t] = ob2[16 * t + lr]; }
    const float o3r = ob3[lr];

    __syncthreads();

    for (int step = 0; step < 2; ++step) {
        // ----- edge phase: wave (w01,kw) -> receivers 16*w01..+15, component kw.
        // Layer1 transposed (D1 = h1^T with pi-permuted cols) => D1 regs ARE the
        // layer2 A-frags after relu+pack. No LDS, no shuffles between layers.
        for (int p = 0; p < 16; ++p) {
            const int ir = 16 * w01 + p;
            float racc[4] = {0.f, 0.f, 0.f, 0.f};
#pragma unroll
            for (int half = 0; half < 2; ++half) {
                const int m = 2 * ir + half;
                const int e0 = m * 16;
                const int srow = (g < 2) ? (16 * (m & 1) + lr) : (m >> 1);
                const bf16x8 bfrag = *(const bf16x8*)(&xsb[srow][(g & 1) * 8]);

                float ewv[4];
#pragma unroll
                for (int r = 0; r < 4; ++r) ewv[r] = ew[(e0 + 4 * g + r) * 2 + kw];

                // layer1 (K=32, bias via C-init): c[t][r] = h1pre[e0+lr][pi(t,g,r)]
                f32x4 c0 = __builtin_amdgcn_mfma_f32_16x16x32_bf16(w1t[0], bfrag, b1c[0], 0, 0, 0);
                f32x4 c1 = __builtin_amdgcn_mfma_f32_16x16x32_bf16(w1t[1], bfrag, b1c[1], 0, 0, 0);
                f32x4 c2 = __builtin_amdgcn_mfma_f32_16x16x32_bf16(w1t[2], bfrag, b1c[2], 0, 0, 0);
                f32x4 c3 = __builtin_amdgcn_mfma_f32_16x16x32_bf16(w1t[3], bfrag, b1c[3], 0, 0, 0);

                // relu + pack: pk in t-order = the two layer2 A-frags
                union { u32 u[8]; bf16x8 v[2]; } a2;
                a2.u[0] = cvtpk(fmaxf(c0[0], 0.f), fmaxf(c0[1], 0.f));
                a2.u[1] = cvtpk(fmaxf(c0[2], 0.f), fmaxf(c0[3], 0.f));
                a2.u[2] = cvtpk(fmaxf(c1[0], 0.f), fmaxf(c1[1], 0.f));
                a2.u[3] = cvtpk(fmaxf(c1[2], 0.f), fmaxf(c1[3], 0.f));
                a2.u[4] = cvtpk(fmaxf(c2[0], 0.f), fmaxf(c2[1], 0.f));
                a2.u[5] = cvtpk(fmaxf(c2[2], 0.f), fmaxf(c2[3], 0.f));
                a2.u[6] = cvtpk(fmaxf(c3[0], 0.f), fmaxf(c3[1], 0.f));
                a2.u[7] = cvtpk(fmaxf(c3[2], 0.f), fmaxf(c3[3], 0.f));

                // layer2 (K=64, bias via C-init); accumulate weighted edge sum
#pragma unroll
                for (int t = 0; t < 4; ++t) {
                    f32x4 d = {b2r[t], b2r[t], b2r[t], b2r[t]};
                    d = __builtin_amdgcn_mfma_f32_16x16x32_bf16(a2.v[0], w2f[0][t], d, 0, 0, 0);
                    d = __builtin_amdgcn_mfma_f32_16x16x32_bf16(a2.v[1], w2f[1][t], d, 0, 0, 0);
#pragma unroll
                    for (int r = 0; r < 4; ++r)
                        racc[t] += fmaxf(d[r], 0.f) * ewv[r];
                }
            }
            // reduce over g (16 edges done: 4 in-lane + cross-g butterfly)
#pragma unroll
            for (int t = 0; t < 4; ++t) {
                racc[t] += __shfl_xor(racc[t], 16);
                racc[t] += __shfl_xor(racc[t], 32);
            }
            float v = (g & 2) ? ((g & 1) ? racc[3] : racc[2])
                              : ((g & 1) ? racc[1] : racc[0]);
            agg2[kw][ir][16 * g + lr] = v;
        }
        __syncthreads();

        // ----- augb agg-part: sum the two k-planes, convert to bf16
        {
            const int a = tid >> 3, cc = (tid & 7) * 8;
            f32x4 x0 = *(const f32x4*)&agg2[0][a][cc];
            f32x4 x1 = *(const f32x4*)&agg2[0][a][cc + 4];
            f32x4 y0 = *(const f32x4*)&agg2[1][a][cc];
            f32x4 y1 = *(const f32x4*)&agg2[1][a][cc + 4];
            x0 += y0; x1 += y1;
            u32x4 q = { cvtpk(x0[0], x0[1]), cvtpk(x0[2], x0[3]),
                        cvtpk(x1[0], x1[1]), cvtpk(x1[2], x1[3]) };
            *(u32x4*)&augb[a][16 + cc] = q;
        }
        __syncthreads();

        // ----- out layer 1 (80->64): wave w = N-tile w
        {
            f32x4 c0 = {o1r[w], o1r[w], o1r[w], o1r[w]};
            f32x4 c1 = c0;
#pragma unroll
            for (int s = 0; s < 3; ++s) {
                const bf16x8 a0 = *(const bf16x8*)(&augb[lr][32 * s + 8 * g]);
                const bf16x8 a1 = *(const bf16x8*)(&augb[16 + lr][32 * s + 8 * g]);
                const bf16x8 bw = *(const bf16x8*)(ow1p + ((s * 4 + w) * 64 + lane) * 8);
                c0 = __builtin_amdgcn_mfma_f32_16x16x32_bf16(a0, bw, c0, 0, 0, 0);
                c1 = __builtin_amdgcn_mfma_f32_16x16x32_bf16(a1, bw, c1, 0, 0, 0);
            }
#pragma unroll
            for (int r = 0; r < 4; ++r) {
                p1b[4 * g + r][16 * w + lr]      = f2bf1(fmaxf(c0[r], 0.f));
                p1b[16 + 4 * g + r][16 * w + lr] = f2bf1(fmaxf(c1[r], 0.f));
            }
        }
        __syncthreads();

        // ----- out layer 2 (64->64)
        {
            f32x4 c0 = {o2r[w], o2r[w], o2r[w], o2r[w]};
            f32x4 c1 = c0;
#pragma unroll
            for (int s = 0; s < 2; ++s) {
                const bf16x8 a0 = *(const bf16x8*)(&p1b[lr][32 * s + 8 * g]);
                const bf16x8 a1 = *(const bf16x8*)(&p1b[16 + lr][32 * s + 8 * g]);
                const bf16x8 bw = *(const bf16x8*)(ow2p + ((s * 4 + w) * 64 + lane) * 8);
                c0 = __builtin_amdgcn_mfma_f32_16x16x32_bf16(a0, bw, c0, 0, 0, 0);
                c1 = __builtin_amdgcn_mfma_f32_16x16x32_bf16(a1, bw, c1, 0, 0, 0);
            }
#pragma unroll
            for (int r = 0; r < 4; ++r) {
                p2b[4 * g + r][16 * w + lr]      = f2bf1(fmaxf(c0[r], 0.f));
                p2b[16 + 4 * g + r][16 * w + lr] = f2bf1(fmaxf(c1[r], 0.f));
            }
        }
        __syncthreads();

        // ----- out layer 3 (64->16) + residual + store; waves 0,1 = M-tiles
        if (w < 2) {
            f32x4 c = {o3r, o3r, o3r, o3r};
#pragma unroll
            for (int s = 0; s < 2; ++s) {
                const bf16x8 a0 = *(const bf16x8*)(&p2b[16 * w + lr][32 * s + 8 * g]);
                const bf16x8 bw = *(const bf16x8*)(ow3p + (s * 64 + lane) * 8);
                c = __builtin_amdgcn_mfma_f32_16x16x32_bf16(a0, bw, c, 0, 0, 0);
            }
            const int tt = 2 * tp + step;
#pragma unroll
            for (int r = 0; r < 4; ++r) {
                const int aa = 16 * w + 4 * g + r;
                const float nv = xsf[aa][lr] + c[r];
                u16 bv = f2bf1(nv);
                xsf[aa][lr] = nv;
                xsb[aa][lr] = bv;
                augb[aa][lr] = bv;
                if (tt < 63) out[(((b * 32 + aa) * 63) + tt) * 16 + lr] = nv;
            }
        }
        __syncthreads();
    }
}

extern "C" void kernel_launch(void* const* d_in, const int* in_sizes, int n_in,
                              void* d_out, int out_size, void* d_ws, size_t ws_size,
                              hipStream_t stream) {
    const float* inputs = (const float*)d_in[0];
    const float* rg     = (const float*)d_in[3];
    const float* gb     = (const float*)d_in[4];
    const float* W1     = (const float*)d_in[5];
    const float* mb1    = (const float*)d_in[6];
    const float* W2     = (const float*)d_in[7];
    const float* mb2    = (const float*)d_in[8];
    const float* OW1    = (const float*)d_in[9];
    const float* ob1    = (const float*)d_in[10];
    const float* OW2    = (const float*)d_in[11];
    const float* ob2    = (const float*)d_in[12];
    const float* OW3    = (const float*)d_in[13];
    const float* ob3    = (const float*)d_in[14];

    float* ew = (float*)d_ws;                       // 1024*2 f32 = 8 KiB
    u16*   wpk = (u16*)((char*)d_ws + 8192);        // 23552 u16 ~= 46 KiB

    edge_softmax_k<<<4, 256, 0, stream>>>(rg, gb, ew);
    pack_weights_k<<<92, 256, 0, stream>>>(W1, W2, OW1, OW2, OW3, wpk);
    nri_decoder_k<<<1024, 256, 0, stream>>>(inputs, mb1, mb2, ob1, ob2, ob3,
                                            ew, wpk, (float*)d_out);
}

// Round 5
// 90.705 us; speedup vs baseline: 1.0935x; 1.0935x over previous
//
#include <hip/hip_runtime.h>

typedef unsigned short u16;
typedef unsigned int u32;
typedef __attribute__((ext_vector_type(8))) short bf16x8;
typedef __attribute__((ext_vector_type(4))) float f32x4;
typedef __attribute__((ext_vector_type(4))) u32 u32x4;

__device__ __forceinline__ u32 cvtpk(float lo, float hi) {
    u32 r; asm("v_cvt_pk_bf16_f32 %0, %1, %2" : "=v"(r) : "v"(lo), "v"(hi)); return r;
}
__device__ __forceinline__ u16 f2bf1(float f) { return (u16)(cvtpk(f, f) & 0xffffu); }

__device__ __forceinline__ u16 f2bf(float f) {   // setup kernels only
    union { float f; unsigned u; } v; v.f = f;
    unsigned r = (v.u + 0x7FFFu + ((v.u >> 16) & 1u)) >> 16;
    return (u16)r;
}

// ---------------- setup kernel 1: edge softmax into ws (padded 32x32 grid) ---
__global__ void edge_softmax_k(const float* __restrict__ rg,
                               const float* __restrict__ gb,
                               float* __restrict__ ew) {
    int tid = blockIdx.x * 256 + threadIdx.x;      // 0..1023 = i*32+j
    if (tid >= 1024) return;
    int i = tid >> 5, j = tid & 31;
    float w0 = 0.f, w1 = 0.f;
    if (i != j) {
        int e = i * 31 + j - (j > i ? 1 : 0);      // original edge index
        float a0 = (rg[e * 2 + 0] + gb[e * 2 + 0]) * 2.0f;   // /TAU, TAU=0.5
        float a1 = (rg[e * 2 + 1] + gb[e * 2 + 1]) * 2.0f;
        float m = fmaxf(a0, a1);
        float e0 = expf(a0 - m), e1 = expf(a1 - m);
        float s = e0 + e1;
        w0 = e0 / s; w1 = e1 / s;
    }
    ew[tid * 2 + 0] = w0;
    ew[tid * 2 + 1] = w1;
}

// ---------------- setup kernel 2: pack weights into MFMA fragment order ------
// B-frag (16x16x32): lane l supplies B[32*s + 8*(l>>4) + j][16*t + (l&15)]
// w1tp: A-frag of W1^T with output-col permutation pi(t,a,b)=32(t>>1)+8a+4(t&1)+b
//       lane l, elem j: W1[k][8*(l>>4)+j][pi(t, (l&15)>>2, l&3)]
__global__ void pack_weights_k(const float* __restrict__ W1,   // (2,32,64)
                               const float* __restrict__ W2,   // (2,64,64)
                               const float* __restrict__ OW1,  // (80,64)
                               const float* __restrict__ OW2,  // (64,64)
                               const float* __restrict__ OW3,  // (64,16)
                               u16* __restrict__ wp) {
    int tid = blockIdx.x * 256 + threadIdx.x;
    if (tid < 4096) {                                     // w1tp [k][t][lane][8]
        int j = tid & 7, l = (tid >> 3) & 63, t = (tid >> 9) & 3, k = tid >> 11;
        int kk = 8 * (l >> 4) + j;
        int n  = 32 * (t >> 1) + 8 * ((l & 15) >> 2) + 4 * (t & 1) + (l & 3);
        wp[tid] = f2bf(W1[k * 2048 + kk * 64 + n]);
    } else if (tid < 12288) {                             // w2p [k][s][t][lane][8]
        int x = tid - 4096;
        int j = x & 7, l = (x >> 3) & 63, t = (x >> 9) & 3, s = (x >> 11) & 1, k = x >> 12;
        int kk = 32 * s + 8 * (l >> 4) + j, n = 16 * t + (l & 15);
        wp[tid] = f2bf(W2[k * 4096 + kk * 64 + n]);
    } else if (tid < 18432) {                             // ow1p [s3][t][lane][8], K=80 pad 96
        int x = tid - 12288;
        int j = x & 7, l = (x >> 3) & 63, t = (x >> 9) & 3, s = x >> 11;
        int kk = 32 * s + 8 * (l >> 4) + j, n = 16 * t + (l & 15);
        wp[tid] = f2bf(kk < 80 ? OW1[kk * 64 + n] : 0.f);
    } else if (tid < 22528) {                             // ow2p [s2][t][lane][8]
        int x = tid - 18432;
        int j = x & 7, l = (x >> 3) & 63, t = (x >> 9) & 3, s = x >> 11;
        int kk = 32 * s + 8 * (l >> 4) + j, n = 16 * t + (l & 15);
        wp[tid] = f2bf(OW2[kk * 64 + n]);
    } else if (tid < 23552) {                             // ow3p [s2][lane][8], N=16
        int x = tid - 22528;
        int j = x & 7, l = (x >> 3) & 63, s = x >> 9;
        int kk = 32 * s + 8 * (l >> 4) + j, n = (l & 15);
        wp[tid] = f2bf(OW3[kk * 16 + n]);
    }
}

// ---------------- main fused kernel: one block per (b, tp) -------------------
// (256,2): residency is reg-file-bound at 2 waves/SIMD regardless (VGPR+AGPR
// total in (128,256] bucket, m69 pow2 quantum); this hint gives the best
// codegen. (256,4) miscompiles (NaN, forced <=128 budget); no hint = 19% slower.
__global__ __launch_bounds__(256, 2) void nri_decoder_k(
    const float* __restrict__ inputs,   // (32,32,64,16)
    const float* __restrict__ mb1, const float* __restrict__ mb2,
    const float* __restrict__ ob1, const float* __restrict__ ob2,
    const float* __restrict__ ob3,
    const float* __restrict__ ew,       // (1024,2) padded edge weights
    const u16*  __restrict__ wp,        // packed weights
    float* __restrict__ out)            // (32,32,63,16)
{
    __shared__ float xsf[32][16];
    __shared__ __align__(16) u16 xsb[32][24];       // 48B rows
    __shared__ __align__(16) float agg2[2][32][68]; // per-k partial agg, 272B rows
    __shared__ __align__(16) u16 augb[32][104];     // [xs16|agg64|pad16], 208B rows
    __shared__ __align__(16) u16 p1b[32][72];
    __shared__ __align__(16) u16 p2b[32][72];

    const int tid = threadIdx.x;
    const int w = tid >> 6, lane = tid & 63, g = lane >> 4, lr = lane & 15;
    const int kw = w >> 1, w01 = w & 1;             // wave's k-component / receiver half
    const int b = blockIdx.x >> 5, tp = blockIdx.x & 31;

    const u16* w1tp = wp;
    const u16* w2p  = wp + 4096;
    const u16* ow1p = wp + 12288;
    const u16* ow2p = wp + 18432;
    const u16* ow3p = wp + 22528;

    // load xs (timestep 2*tp); init augb xs-part and zero pad
    for (int idx = tid; idx < 512; idx += 256) {
        int a = idx >> 4, d = idx & 15;
        float v = inputs[(((b * 32 + a) * 64) + 2 * tp) * 16 + d];
        u16 bv = f2bf1(v);
        xsf[a][d] = v;
        xsb[a][d] = bv;
        augb[a][d] = bv;
        augb[a][80 + d] = 0;
    }

    // per-wave persistent fragments (k = kw only)
    bf16x8 w1t[4], w2f[2][4];
#pragma unroll
    for (int t = 0; t < 4; ++t)
        w1t[t] = *(const bf16x8*)(w1tp + ((kw * 4 + t) * 64 + lane) * 8);
#pragma unroll
    for (int s = 0; s < 2; ++s)
#pragma unroll
        for (int t = 0; t < 4; ++t)
            w2f[s][t] = *(const bf16x8*)(w2p + (((kw * 2 + s) * 4 + t) * 64 + lane) * 8);

    f32x4 b1c[4];
    float b2r[4];
#pragma unroll
    for (int t = 0; t < 4; ++t) {
#pragma unroll
        for (int r = 0; r < 4; ++r)
            b1c[t][r] = mb1[kw * 64 + 32 * (t >> 1) + 8 * g + 4 * (t & 1) + r];
        b2r[t] = mb2[kw * 64 + 16 * t + lr];
    }
    float o1r[4], o2r[4];
#pragma unroll
    for (int t = 0; t < 4; ++t) { o1r[t] = ob1[16 * t + lr]; o2r[t] = ob2[16 * t + lr]; }
    const float o3r = ob3[lr];

    __syncthreads();

    for (int step = 0; step < 2; ++step) {
        // ----- edge phase: wave (w01,kw) -> receivers 16*w01..+15, component kw.
        // Layer1 transposed (D1 = h1^T with pi-permuted cols) => D1 regs ARE the
        // layer2 A-frags after relu+pack. No LDS, no shuffles between layers.
        // p-iterations are independent: 2-way unroll gives the scheduler two
        // chains to interleave (latency hiding at 2 waves/SIMD).
#pragma unroll 2
        for (int p = 0; p < 16; ++p) {
            const int ir = 16 * w01 + p;
            float racc[4] = {0.f, 0.f, 0.f, 0.f};
#pragma unroll
            for (int half = 0; half < 2; ++half) {
                const int m = 2 * ir + half;
                const int e0 = m * 16;
                const int srow = (g < 2) ? (16 * (m & 1) + lr) : (m >> 1);
                const bf16x8 bfrag = *(const bf16x8*)(&xsb[srow][(g & 1) * 8]);

                float ewv[4];
#pragma unroll
                for (int r = 0; r < 4; ++r) ewv[r] = ew[(e0 + 4 * g + r) * 2 + kw];

                // layer1 (K=32, bias via C-init): c[t][r] = h1pre[e0+lr][pi(t,g,r)]
                f32x4 c0 = __builtin_amdgcn_mfma_f32_16x16x32_bf16(w1t[0], bfrag, b1c[0], 0, 0, 0);
                f32x4 c1 = __builtin_amdgcn_mfma_f32_16x16x32_bf16(w1t[1], bfrag, b1c[1], 0, 0, 0);
                f32x4 c2 = __builtin_amdgcn_mfma_f32_16x16x32_bf16(w1t[2], bfrag, b1c[2], 0, 0, 0);
                f32x4 c3 = __builtin_amdgcn_mfma_f32_16x16x32_bf16(w1t[3], bfrag, b1c[3], 0, 0, 0);

                // relu + pack: pk in t-order = the two layer2 A-frags
                union { u32 u[8]; bf16x8 v[2]; } a2;
                a2.u[0] = cvtpk(fmaxf(c0[0], 0.f), fmaxf(c0[1], 0.f));
                a2.u[1] = cvtpk(fmaxf(c0[2], 0.f), fmaxf(c0[3], 0.f));
                a2.u[2] = cvtpk(fmaxf(c1[0], 0.f), fmaxf(c1[1], 0.f));
                a2.u[3] = cvtpk(fmaxf(c1[2], 0.f), fmaxf(c1[3], 0.f));
                a2.u[4] = cvtpk(fmaxf(c2[0], 0.f), fmaxf(c2[1], 0.f));
                a2.u[5] = cvtpk(fmaxf(c2[2], 0.f), fmaxf(c2[3], 0.f));
                a2.u[6] = cvtpk(fmaxf(c3[0], 0.f), fmaxf(c3[1], 0.f));
                a2.u[7] = cvtpk(fmaxf(c3[2], 0.f), fmaxf(c3[3], 0.f));

                // layer2 (K=64, bias via C-init); accumulate weighted edge sum
#pragma unroll
                for (int t = 0; t < 4; ++t) {
                    f32x4 d = {b2r[t], b2r[t], b2r[t], b2r[t]};
                    d = __builtin_amdgcn_mfma_f32_16x16x32_bf16(a2.v[0], w2f[0][t], d, 0, 0, 0);
                    d = __builtin_amdgcn_mfma_f32_16x16x32_bf16(a2.v[1], w2f[1][t], d, 0, 0, 0);
#pragma unroll
                    for (int r = 0; r < 4; ++r)
                        racc[t] += fmaxf(d[r], 0.f) * ewv[r];
                }
            }
            // reduce over g (16 edges done: 4 in-lane + cross-g butterfly)
#pragma unroll
            for (int t = 0; t < 4; ++t) {
                racc[t] += __shfl_xor(racc[t], 16);
                racc[t] += __shfl_xor(racc[t], 32);
            }
            float v = (g & 2) ? ((g & 1) ? racc[3] : racc[2])
                              : ((g & 1) ? racc[1] : racc[0]);
            agg2[kw][ir][16 * g + lr] = v;
        }
        __syncthreads();

        // ----- augb agg-part: sum the two k-planes, convert to bf16
        {
            const int a = tid >> 3, cc = (tid & 7) * 8;
            f32x4 x0 = *(const f32x4*)&agg2[0][a][cc];
            f32x4 x1 = *(const f32x4*)&agg2[0][a][cc + 4];
            f32x4 y0 = *(const f32x4*)&agg2[1][a][cc];
            f32x4 y1 = *(const f32x4*)&agg2[1][a][cc + 4];
            x0 += y0; x1 += y1;
            u32x4 q = { cvtpk(x0[0], x0[1]), cvtpk(x0[2], x0[3]),
                        cvtpk(x1[0], x1[1]), cvtpk(x1[2], x1[3]) };
            *(u32x4*)&augb[a][16 + cc] = q;
        }
        __syncthreads();

        // ----- out layer 1 (80->64): wave w = N-tile w
        {
            f32x4 c0 = {o1r[w], o1r[w], o1r[w], o1r[w]};
            f32x4 c1 = c0;
#pragma unroll
            for (int s = 0; s < 3; ++s) {
                const bf16x8 a0 = *(const bf16x8*)(&augb[lr][32 * s + 8 * g]);
                const bf16x8 a1 = *(const bf16x8*)(&augb[16 + lr][32 * s + 8 * g]);
                const bf16x8 bw = *(const bf16x8*)(ow1p + ((s * 4 + w) * 64 + lane) * 8);
                c0 = __builtin_amdgcn_mfma_f32_16x16x32_bf16(a0, bw, c0, 0, 0, 0);
                c1 = __builtin_amdgcn_mfma_f32_16x16x32_bf16(a1, bw, c1, 0, 0, 0);
            }
#pragma unroll
            for (int r = 0; r < 4; ++r) {
                p1b[4 * g + r][16 * w + lr]      = f2bf1(fmaxf(c0[r], 0.f));
                p1b[16 + 4 * g + r][16 * w + lr] = f2bf1(fmaxf(c1[r], 0.f));
            }
        }
        __syncthreads();

        // ----- out layer 2 (64->64)
        {
            f32x4 c0 = {o2r[w], o2r[w], o2r[w], o2r[w]};
            f32x4 c1 = c0;
#pragma unroll
            for (int s = 0; s < 2; ++s) {
                const bf16x8 a0 = *(const bf16x8*)(&p1b[lr][32 * s + 8 * g]);
                const bf16x8 a1 = *(const bf16x8*)(&p1b[16 + lr][32 * s + 8 * g]);
                const bf16x8 bw = *(const bf16x8*)(ow2p + ((s * 4 + w) * 64 + lane) * 8);
                c0 = __builtin_amdgcn_mfma_f32_16x16x32_bf16(a0, bw, c0, 0, 0, 0);
                c1 = __builtin_amdgcn_mfma_f32_16x16x32_bf16(a1, bw, c1, 0, 0, 0);
            }
#pragma unroll
            for (int r = 0; r < 4; ++r) {
                p2b[4 * g + r][16 * w + lr]      = f2bf1(fmaxf(c0[r], 0.f));
                p2b[16 + 4 * g + r][16 * w + lr] = f2bf1(fmaxf(c1[r], 0.f));
            }
        }
        __syncthreads();

        // ----- out layer 3 (64->16) + residual + store; waves 0,1 = M-tiles
        if (w < 2) {
            f32x4 c = {o3r, o3r, o3r, o3r};
#pragma unroll
            for (int s = 0; s < 2; ++s) {
                const bf16x8 a0 = *(const bf16x8*)(&p2b[16 * w + lr][32 * s + 8 * g]);
                const bf16x8 bw = *(const bf16x8*)(ow3p + (s * 64 + lane) * 8);
                c = __builtin_amdgcn_mfma_f32_16x16x32_bf16(a0, bw, c, 0, 0, 0);
            }
            const int tt = 2 * tp + step;
#pragma unroll
            for (int r = 0; r < 4; ++r) {
                const int aa = 16 * w + 4 * g + r;
                const float nv = xsf[aa][lr] + c[r];
                u16 bv = f2bf1(nv);
                xsf[aa][lr] = nv;
                xsb[aa][lr] = bv;
                augb[aa][lr] = bv;
                if (tt < 63) out[(((b * 32 + aa) * 63) + tt) * 16 + lr] = nv;
            }
        }
        __syncthreads();
    }
}

extern "C" void kernel_launch(void* const* d_in, const int* in_sizes, int n_in,
                              void* d_out, int out_size, void* d_ws, size_t ws_size,
                              hipStream_t stream) {
    const float* inputs = (const float*)d_in[0];
    const float* rg     = (const float*)d_in[3];
    const float* gb     = (const float*)d_in[4];
    const float* W1     = (const float*)d_in[5];
    const float* mb1    = (const float*)d_in[6];
    const float* W2     = (const float*)d_in[7];
    const float* mb2    = (const float*)d_in[8];
    const float* OW1    = (const float*)d_in[9];
    const float* ob1    = (const float*)d_in[10];
    const float* OW2    = (const float*)d_in[11];
    const float* ob2    = (const float*)d_in[12];
    const float* OW3    = (const float*)d_in[13];
    const float* ob3    = (const float*)d_in[14];

    float* ew = (float*)d_ws;                       // 1024*2 f32 = 8 KiB
    u16*   wpk = (u16*)((char*)d_ws + 8192);        // 23552 u16 ~= 46 KiB

    edge_softmax_k<<<4, 256, 0, stream>>>(rg, gb, ew);
    pack_weights_k<<<92, 256, 0, stream>>>(W1, W2, OW1, OW2, OW3, wpk);
    nri_decoder_k<<<1024, 256, 0, stream>>>(inputs, mb1, mb2, ob1, ob2, ob3,
                                            ew, wpk, (float*)d_out);
}

// Round 6
// 82.328 us; speedup vs baseline: 1.2048x; 1.1018x over previous
//
#include <hip/hip_runtime.h>

typedef unsigned short u16;
typedef unsigned int u32;
typedef __attribute__((ext_vector_type(8))) short bf16x8;
typedef __attribute__((ext_vector_type(4))) float f32x4;
typedef __attribute__((ext_vector_type(2))) u32 u32x2;
typedef __attribute__((ext_vector_type(4))) u32 u32x4;

__device__ __forceinline__ u32 cvtpk(float lo, float hi) {
    u32 r; asm("v_cvt_pk_bf16_f32 %0, %1, %2" : "=v"(r) : "v"(lo), "v"(hi)); return r;
}

__device__ __forceinline__ u16 f2bf(float f) {   // setup kernels only
    union { float f; unsigned u; } v; v.f = f;
    unsigned r = (v.u + 0x7FFFu + ((v.u >> 16) & 1u)) >> 16;
    return (u16)r;
}

// ---------------- setup kernel 1: edge softmax into ws (padded 32x32 grid) ---
__global__ void edge_softmax_k(const float* __restrict__ rg,
                               const float* __restrict__ gb,
                               float* __restrict__ ew) {
    int tid = blockIdx.x * 256 + threadIdx.x;      // 0..1023 = i*32+j
    if (tid >= 1024) return;
    int i = tid >> 5, j = tid & 31;
    float w0 = 0.f, w1 = 0.f;
    if (i != j) {
        int e = i * 31 + j - (j > i ? 1 : 0);      // original edge index
        float a0 = (rg[e * 2 + 0] + gb[e * 2 + 0]) * 2.0f;   // /TAU, TAU=0.5
        float a1 = (rg[e * 2 + 1] + gb[e * 2 + 1]) * 2.0f;
        float m = fmaxf(a0, a1);
        float e0 = expf(a0 - m), e1 = expf(a1 - m);
        float s = e0 + e1;
        w0 = e0 / s; w1 = e1 / s;
    }
    ew[tid * 2 + 0] = w0;
    ew[tid * 2 + 1] = w1;
}

// ---------------- setup kernel 2: pack weights into MFMA fragment order ------
// frag (16x16x32), A and B symmetric: lane l supplies [nonK = l&15][k = 8*(l>>4)+j]
// pi(t,a,b) = 32*(t>>1) + 8*a + 4*(t&1) + b   (output-col permutation so packed
// D regs in t-order are the NEXT layer's frag; proven by the msg-MLP chain)
__global__ void pack_weights_k(const float* __restrict__ W1,   // (2,32,64)
                               const float* __restrict__ W2,   // (2,64,64)
                               const float* __restrict__ OW1,  // (80,64)
                               const float* __restrict__ OW2,  // (64,64)
                               const float* __restrict__ OW3,  // (64,16)
                               u16* __restrict__ wp) {
    int tid = blockIdx.x * 256 + threadIdx.x;
    if (tid < 4096) {                                     // w1tp [k][t][lane][8]
        int j = tid & 7, l = (tid >> 3) & 63, t = (tid >> 9) & 3, k = tid >> 11;
        int kk = 8 * (l >> 4) + j;
        int n  = 32 * (t >> 1) + 8 * ((l & 15) >> 2) + 4 * (t & 1) + (l & 3);
        wp[tid] = f2bf(W1[k * 2048 + kk * 64 + n]);
    } else if (tid < 12288) {                             // w2p [k][s][t][lane][8]
        int x = tid - 4096;
        int j = x & 7, l = (x >> 3) & 63, t = (x >> 9) & 3, s = (x >> 11) & 1, k = x >> 12;
        int kk = 32 * s + 8 * (l >> 4) + j, n = 16 * t + (l & 15);
        wp[tid] = f2bf(W2[k * 4096 + kk * 64 + n]);
    } else if (tid < 18432) {                             // ow1t [t][s3][lane][8]: OW1^T A-frag, pi cols, K=80 pad 96
        int x = tid - 12288;
        int j = x & 7, l = (x >> 3) & 63, ts = x >> 9;    // ts = t*3+s
        int s = ts % 3, t = ts / 3;
        int kk = 32 * s + 8 * (l >> 4) + j;
        int feat = 32 * (t >> 1) + 8 * ((l & 15) >> 2) + 4 * (t & 1) + (l & 3);
        wp[tid] = f2bf(kk < 80 ? OW1[kk * 64 + feat] : 0.f);
    } else if (tid < 22528) {                             // ow2t [t][s2][lane][8]: OW2^T A-frag, pi cols
        int x = tid - 18432;
        int j = x & 7, l = (x >> 3) & 63, ts = x >> 9;    // ts = t*2+s
        int s = ts & 1, t = ts >> 1;
        int kk = 32 * s + 8 * (l >> 4) + j;
        int feat = 32 * (t >> 1) + 8 * ((l & 15) >> 2) + 4 * (t & 1) + (l & 3);
        wp[tid] = f2bf(OW2[kk * 64 + feat]);
    } else if (tid < 23552) {                             // ow3t [s2][lane][8]: OW3^T A-frag, plain cols
        int x = tid - 22528;
        int j = x & 7, l = (x >> 3) & 63, s = x >> 9;
        int kk = 32 * s + 8 * (l >> 4) + j;
        wp[tid] = f2bf(OW3[kk * 16 + (l & 15)]);
    }
}

// ---------------- main fused kernel: one block per (b, tp) -------------------
// (256,2): residency is reg-file-bound at 2 waves/SIMD (VGPR+AGPR bucket);
// this hint gives the best codegen ((256,4) miscompiles, no-hint is slower).
__global__ __launch_bounds__(256, 2) void nri_decoder_k(
    const float* __restrict__ inputs,   // (32,32,64,16)
    const float* __restrict__ mb1, const float* __restrict__ mb2,
    const float* __restrict__ ob1, const float* __restrict__ ob2,
    const float* __restrict__ ob3,
    const float* __restrict__ ew,       // (1024,2) padded edge weights
    const u16*  __restrict__ wp,        // packed weights
    float* __restrict__ out)            // (32,32,63,16)
{
    __shared__ __align__(16) u16 xsb[2][32][24];    // bf16 xs, step-parity planes
    __shared__ __align__(16) float agg2[2][32][68]; // per-k partial agg
    __shared__ __align__(16) u16 augb[2][32][104];  // [xs16|agg64|pad16], planes
    __shared__ __align__(16) u16 owlds[11264];      // ow1t(6144)|ow2t(4096)|ow3t(1024)

    const int tid = threadIdx.x;
    const int w = tid >> 6, lane = tid & 63, g = lane >> 4, lr = lane & 15;
    const int kw = w >> 1, w01 = w & 1;
    const int b = blockIdx.x >> 5, tp = blockIdx.x & 31;

    const u16* w1tp = wp;
    const u16* w2p  = wp + 4096;

    // stage packed out-weights into LDS (1408 x 16B)
    for (int idx = tid; idx < 1408; idx += 256)
        *(u32x4*)(&owlds[idx * 8]) = *(const u32x4*)(wp + 12288 + idx * 8);

    // load xs (timestep 2*tp) -> xsb[0], augb[0] xs-part (vectorized f32x4)
    if (tid < 128) {
        const int a = tid >> 2, dd = (tid & 3) * 4;
        const f32x4 v = *(const f32x4*)(inputs + (((b * 32 + a) * 64) + 2 * tp) * 16 + dd);
        u32x2 q = { cvtpk(v[0], v[1]), cvtpk(v[2], v[3]) };
        *(u32x2*)(&xsb[0][a][dd]) = q;
        *(u32x2*)(&augb[0][a][dd]) = q;
    }
    // zero pad cols 80..95 of both augb planes
    for (int idx = tid; idx < 1024; idx += 256)
        augb[idx >> 9][(idx >> 4) & 31][80 + (idx & 15)] = 0;

    // per-wave persistent fragments (k = kw for the msg MLP)
    bf16x8 w1t[4], w2f[2][4];
#pragma unroll
    for (int t = 0; t < 4; ++t)
        w1t[t] = *(const bf16x8*)(w1tp + ((kw * 4 + t) * 64 + lane) * 8);
#pragma unroll
    for (int s = 0; s < 2; ++s)
#pragma unroll
        for (int t = 0; t < 4; ++t)
            w2f[s][t] = *(const bf16x8*)(w2p + (((kw * 2 + s) * 4 + t) * 64 + lane) * 8);

    f32x4 b1c[4], o1c[4], o2c[4], o3c;
    float b2r[4];
#pragma unroll
    for (int t = 0; t < 4; ++t) {
#pragma unroll
        for (int r = 0; r < 4; ++r) {
            const int pi = 32 * (t >> 1) + 8 * g + 4 * (t & 1) + r;
            b1c[t][r] = mb1[kw * 64 + pi];
            o1c[t][r] = ob1[pi];
            o2c[t][r] = ob2[pi];
        }
        b2r[t] = mb2[kw * 64 + 16 * t + lr];
    }
#pragma unroll
    for (int r = 0; r < 4; ++r) o3c[r] = ob3[4 * g + r];

    // residual xs state in registers: this wave's agents 16*(w&1)+lr, feats 4g..
    const int u = w & 1;
    const int arow = 16 * u + lr;
    f32x4 xsreg = *(const f32x4*)(inputs + (((b * 32 + arow) * 64) + 2 * tp) * 16 + 4 * g);

    __syncthreads();

    for (int step = 0; step < 2; ++step) {
        const int sp = step & 1;

        // ----- edge phase (unchanged from r2): wave (w01,kw) -> receivers
        // 16*w01..+15, component kw. Layer1 transposed => D1 regs ARE the
        // layer2 A-frags after relu+pack.
        for (int p = 0; p < 16; ++p) {
            const int ir = 16 * w01 + p;
            float racc[4] = {0.f, 0.f, 0.f, 0.f};
#pragma unroll
            for (int half = 0; half < 2; ++half) {
                const int m = 2 * ir + half;
                const int e0 = m * 16;
                const int srow = (g < 2) ? (16 * (m & 1) + lr) : (m >> 1);
                const bf16x8 bfrag = *(const bf16x8*)(&xsb[sp][srow][(g & 1) * 8]);

                float ewv[4];
#pragma unroll
                for (int r = 0; r < 4; ++r) ewv[r] = ew[(e0 + 4 * g + r) * 2 + kw];

                f32x4 c0 = __builtin_amdgcn_mfma_f32_16x16x32_bf16(w1t[0], bfrag, b1c[0], 0, 0, 0);
                f32x4 c1 = __builtin_amdgcn_mfma_f32_16x16x32_bf16(w1t[1], bfrag, b1c[1], 0, 0, 0);
                f32x4 c2 = __builtin_amdgcn_mfma_f32_16x16x32_bf16(w1t[2], bfrag, b1c[2], 0, 0, 0);
                f32x4 c3 = __builtin_amdgcn_mfma_f32_16x16x32_bf16(w1t[3], bfrag, b1c[3], 0, 0, 0);

                union { u32 q[8]; bf16x8 v[2]; } a2;
                a2.q[0] = cvtpk(fmaxf(c0[0], 0.f), fmaxf(c0[1], 0.f));
                a2.q[1] = cvtpk(fmaxf(c0[2], 0.f), fmaxf(c0[3], 0.f));
                a2.q[2] = cvtpk(fmaxf(c1[0], 0.f), fmaxf(c1[1], 0.f));
                a2.q[3] = cvtpk(fmaxf(c1[2], 0.f), fmaxf(c1[3], 0.f));
                a2.q[4] = cvtpk(fmaxf(c2[0], 0.f), fmaxf(c2[1], 0.f));
                a2.q[5] = cvtpk(fmaxf(c2[2], 0.f), fmaxf(c2[3], 0.f));
                a2.q[6] = cvtpk(fmaxf(c3[0], 0.f), fmaxf(c3[1], 0.f));
                a2.q[7] = cvtpk(fmaxf(c3[2], 0.f), fmaxf(c3[3], 0.f));

#pragma unroll
                for (int t = 0; t < 4; ++t) {
                    f32x4 d = {b2r[t], b2r[t], b2r[t], b2r[t]};
                    d = __builtin_amdgcn_mfma_f32_16x16x32_bf16(a2.v[0], w2f[0][t], d, 0, 0, 0);
                    d = __builtin_amdgcn_mfma_f32_16x16x32_bf16(a2.v[1], w2f[1][t], d, 0, 0, 0);
#pragma unroll
                    for (int r = 0; r < 4; ++r)
                        racc[t] += fmaxf(d[r], 0.f) * ewv[r];
                }
            }
#pragma unroll
            for (int t = 0; t < 4; ++t) {
                racc[t] += __shfl_xor(racc[t], 16);
                racc[t] += __shfl_xor(racc[t], 32);
            }
            float v = (g & 2) ? ((g & 1) ? racc[3] : racc[2])
                              : ((g & 1) ? racc[1] : racc[0]);
            agg2[kw][ir][16 * g + lr] = v;
        }
        __syncthreads();

        // ----- augb agg-part: sum the two k-planes, convert to bf16
        {
            const int a = tid >> 3, cc = (tid & 7) * 8;
            f32x4 x0 = *(const f32x4*)&agg2[0][a][cc];
            f32x4 x1 = *(const f32x4*)&agg2[0][a][cc + 4];
            f32x4 y0 = *(const f32x4*)&agg2[1][a][cc];
            f32x4 y1 = *(const f32x4*)&agg2[1][a][cc + 4];
            x0 += y0; x1 += y1;
            u32x4 q = { cvtpk(x0[0], x0[1]), cvtpk(x0[2], x0[3]),
                        cvtpk(x1[0], x1[1]), cvtpk(x1[2], x1[3]) };
            *(u32x4*)&augb[sp][a][16 + cc] = q;
        }
        __syncthreads();

        // ----- fused out-MLP, transposed in-register chain; wave's half u=w&1.
        // out1^T: D = OW1t · aug^T  (K=96); packed D (pi cols) = out2's B-frag;
        // out2^T likewise feeds out3^T. No LDS between layers, no barriers.
        {
            f32x4 c[4] = {o1c[0], o1c[1], o1c[2], o1c[3]};
#pragma unroll
            for (int s = 0; s < 3; ++s) {
                const bf16x8 bB = *(const bf16x8*)(&augb[sp][arow][32 * s + 8 * g]);
#pragma unroll
                for (int t = 0; t < 4; ++t) {
                    const bf16x8 aA = *(const bf16x8*)(&owlds[(t * 3 + s) * 512 + lane * 8]);
                    c[t] = __builtin_amdgcn_mfma_f32_16x16x32_bf16(aA, bB, c[t], 0, 0, 0);
                }
            }
            union { u32 q[8]; bf16x8 v[2]; } pa;
            pa.q[0] = cvtpk(fmaxf(c[0][0], 0.f), fmaxf(c[0][1], 0.f));
            pa.q[1] = cvtpk(fmaxf(c[0][2], 0.f), fmaxf(c[0][3], 0.f));
            pa.q[2] = cvtpk(fmaxf(c[1][0], 0.f), fmaxf(c[1][1], 0.f));
            pa.q[3] = cvtpk(fmaxf(c[1][2], 0.f), fmaxf(c[1][3], 0.f));
            pa.q[4] = cvtpk(fmaxf(c[2][0], 0.f), fmaxf(c[2][1], 0.f));
            pa.q[5] = cvtpk(fmaxf(c[2][2], 0.f), fmaxf(c[2][3], 0.f));
            pa.q[6] = cvtpk(fmaxf(c[3][0], 0.f), fmaxf(c[3][1], 0.f));
            pa.q[7] = cvtpk(fmaxf(c[3][2], 0.f), fmaxf(c[3][3], 0.f));

            f32x4 c2[4] = {o2c[0], o2c[1], o2c[2], o2c[3]};
#pragma unroll
            for (int s = 0; s < 2; ++s)
#pragma unroll
                for (int t = 0; t < 4; ++t) {
                    const bf16x8 aA = *(const bf16x8*)(&owlds[6144 + (t * 2 + s) * 512 + lane * 8]);
                    c2[t] = __builtin_amdgcn_mfma_f32_16x16x32_bf16(aA, pa.v[s], c2[t], 0, 0, 0);
                }
            union { u32 q[8]; bf16x8 v[2]; } pb;
            pb.q[0] = cvtpk(fmaxf(c2[0][0], 0.f), fmaxf(c2[0][1], 0.f));
            pb.q[1] = cvtpk(fmaxf(c2[0][2], 0.f), fmaxf(c2[0][3], 0.f));
            pb.q[2] = cvtpk(fmaxf(c2[1][0], 0.f), fmaxf(c2[1][1], 0.f));
            pb.q[3] = cvtpk(fmaxf(c2[1][2], 0.f), fmaxf(c2[1][3], 0.f));
            pb.q[4] = cvtpk(fmaxf(c2[2][0], 0.f), fmaxf(c2[2][1], 0.f));
            pb.q[5] = cvtpk(fmaxf(c2[2][2], 0.f), fmaxf(c2[2][3], 0.f));
            pb.q[6] = cvtpk(fmaxf(c2[3][0], 0.f), fmaxf(c2[3][1], 0.f));
            pb.q[7] = cvtpk(fmaxf(c2[3][2], 0.f), fmaxf(c2[3][3], 0.f));

            f32x4 d3 = o3c;
#pragma unroll
            for (int s = 0; s < 2; ++s) {
                const bf16x8 aA = *(const bf16x8*)(&owlds[10240 + s * 512 + lane * 8]);
                d3 = __builtin_amdgcn_mfma_f32_16x16x32_bf16(aA, pb.v[s], d3, 0, 0, 0);
            }

            // residual: lane holds out3pre^T[4g+r][arow]; xsreg = xs[arow][4g+r]
            const f32x4 nv = xsreg + d3;
            xsreg = nv;
            const u32 q0 = cvtpk(nv[0], nv[1]);
            const u32 q1 = cvtpk(nv[2], nv[3]);
            if (w < 2) {                               // waves 0,1: new xs -> LDS plane sp^1
                u32x2 qq = {q0, q1};
                *(u32x2*)(&xsb[sp ^ 1][arow][4 * g]) = qq;
                *(u32x2*)(&augb[sp ^ 1][arow][4 * g]) = qq;
            } else {                                   // waves 2,3: prediction -> global
                const int tt = 2 * tp + step;
                if (tt < 63)
                    *(f32x4*)(out + (((b * 32 + arow) * 63) + tt) * 16 + 4 * g) = nv;
            }
        }
        __syncthreads();
    }
}

extern "C" void kernel_launch(void* const* d_in, const int* in_sizes, int n_in,
                              void* d_out, int out_size, void* d_ws, size_t ws_size,
                              hipStream_t stream) {
    const float* inputs = (const float*)d_in[0];
    const float* rg     = (const float*)d_in[3];
    const float* gb     = (const float*)d_in[4];
    const float* W1     = (const float*)d_in[5];
    const float* mb1    = (const float*)d_in[6];
    const float* W2     = (const float*)d_in[7];
    const float* mb2    = (const float*)d_in[8];
    const float* OW1    = (const float*)d_in[9];
    const float* ob1    = (const float*)d_in[10];
    const float* OW2    = (const float*)d_in[11];
    const float* ob2    = (const float*)d_in[12];
    const float* OW3    = (const float*)d_in[13];
    const float* ob3    = (const float*)d_in[14];

    float* ew = (float*)d_ws;                       // 1024*2 f32 = 8 KiB
    u16*   wpk = (u16*)((char*)d_ws + 8192);        // 23552 u16 ~= 46 KiB

    edge_softmax_k<<<4, 256, 0, stream>>>(rg, gb, ew);
    pack_weights_k<<<92, 256, 0, stream>>>(W1, W2, OW1, OW2, OW3, wpk);
    nri_decoder_k<<<1024, 256, 0, stream>>>(inputs, mb1, mb2, ob1, ob2, ob3,
                                            ew, wpk, (float*)d_out);
}